// Round 5
// baseline (728.421 us; speedup 1.0000x reference)
//
#include <hip/hip_runtime.h>
#include <math.h>

#define B_ 32
#define T_ 2048
#define H_ 1024

typedef __bf16 bf16x8 __attribute__((ext_vector_type(8)));
typedef float f32x4 __attribute__((ext_vector_type(4)));

__device__ __forceinline__ unsigned short f2bf(float f) {
  unsigned int u = __float_as_uint(f);
  u += 0x7fffu + ((u >> 16) & 1u);   // round-to-nearest-even (finite inputs)
  return (unsigned short)(u >> 16);
}

__device__ __forceinline__ float fast_tanh(float x) {
  float e = __expf(2.0f * x);
  return 1.0f - __fdividef(2.0f, e + 1.0f);  // saturates correctly at +-1
}

// Async 16B global -> LDS. LDS dest is wave-uniform base + lane*16 (HW rule).
__device__ __forceinline__ void async16(const void* g, void* l) {
  typedef const __attribute__((address_space(1))) void* gvp;
  typedef __attribute__((address_space(3))) void* lvp;
  __builtin_amdgcn_global_load_lds((gvp)(unsigned long long)g,
                                   (lvp)(unsigned int)(unsigned long long)l,
                                   16, 0, 0);
}

// Small prep: NO ctx conversion pass anymore (score stages ctx fp32 directly).
// blk ranges:
//  [0,256):    hxb — wave per o: Wq row loaded ONCE, loop over b
//  [256,512):  Wm fp32 -> bf16, 4096 floats/block
//  [512,528):  zero logits (4096 floats/block) — score atomicAdds into it
//  [528,536):  zero out_c  (4096 floats/block) — wsum atomicAdds into it
__global__ void prep_kernel(const float* __restrict__ x, const float* __restrict__ Wq,
                            const float* __restrict__ bq, const float* __restrict__ bm,
                            const float* __restrict__ Wm,
                            float* __restrict__ hxb, unsigned short* __restrict__ wmb,
                            float* __restrict__ logits, float* __restrict__ outc) {
  int blk = blockIdx.x, tid = threadIdx.x;
  if (blk < 256) {
    int wave = tid >> 6, lane = tid & 63;
    int o = (blk << 2) + wave;
    const float4* wr = (const float4*)(Wq + (size_t)o * H_);
    float4 wv[4];
#pragma unroll
    for (int s4 = 0; s4 < 4; ++s4) wv[s4] = wr[(s4 << 6) + lane];
    float bias = bq[o] + bm[o];
#pragma unroll 4
    for (int b = 0; b < B_; ++b) {
      const float4* xr = (const float4*)(x + (size_t)b * H_);
      float s = 0.f;
#pragma unroll
      for (int s4 = 0; s4 < 4; ++s4) {
        float4 xv = xr[(s4 << 6) + lane];
        s += wv[s4].x * xv.x + wv[s4].y * xv.y + wv[s4].z * xv.z + wv[s4].w * xv.w;
      }
#pragma unroll
      for (int d = 1; d < 64; d <<= 1) s += __shfl_xor(s, d);
      if (lane == 0) hxb[(b << 10) + o] = s + bias;
    }
  } else if (blk < 512) {
    int i0 = ((blk - 256) << 12) + (tid << 2);
#pragma unroll
    for (int it = 0; it < 4; ++it) {
      int i = i0 + (it << 10);
      float4 wv = *(const float4*)(Wm + i);
      *(ushort4*)(wmb + i) = make_ushort4(f2bf(wv.x), f2bf(wv.y), f2bf(wv.z), f2bf(wv.w));
    }
  } else if (blk < 528) {
    int i0 = ((blk - 512) << 12) + (tid << 2);
#pragma unroll
    for (int it = 0; it < 4; ++it)
      *(float4*)(logits + i0 + (it << 10)) = (float4){0.f, 0.f, 0.f, 0.f};
  } else {
    int i0 = ((blk - 528) << 12) + (tid << 2);
#pragma unroll
    for (int it = 0; it < 4; ++it)
      *(float4*)(outc + i0 + (it << 10)) = (float4){0.f, 0.f, 0.f, 0.f};
  }
}

// Grid 4096: blockIdx.x = ot*512 + b*16 + tt. One 128t x 128o tile per block.
// A is staged as RAW FP32 via global_load_lds (async, no VGPR round-trip — the
// r3 regression was the manual load->cvt->ds_write chain, not fp32 itself).
// fp32 row = 64 k-elems = 16 granules of 16B; swizzle phys = (lg&8)|((lg&7)^(row&7)).
// f32 -> bf16 happens at FRAGMENT-read time (2x ds_read_b128 + 8 HW cvt per frag),
// overlapping the MFMA phase (MfmaUtil 24% -> slack). B (Wm bf16, 2 MB) unchanged.
__global__ __launch_bounds__(256) void score_kernel(
    const float* __restrict__ ctx, const unsigned short* __restrict__ wmb,
    const float* __restrict__ hxb, const float* __restrict__ v,
    float* logits) {
  __shared__ __align__(16) float As[128 * 64];            // 32 KiB (fp32 A-tile)
  __shared__ __align__(16) unsigned short Bs[128 * 64];   // 16 KiB
  __shared__ float part[128];

  int tid = threadIdx.x;
  int xx = blockIdx.x;
  int ot = xx >> 9;
  int bt = xx & 511;
  int b = bt >> 4;
  int t0 = (bt & 15) << 7;
  int o0 = ot << 7;
  if (tid < 128) part[tid] = 0.f;

  int lane = tid & 63;
  int wave = tid >> 6;
  int wm = (wave >> 1) << 6;  // wave t-offset (0/64)
  int wn = (wave & 1) << 6;   // wave o-offset (0/64)
  int q = lane >> 4;
  int m = lane & 15;

  const float* cf = ctx + ((size_t)b * T_ + t0) * H_;
  const unsigned short* wb = wmb + (size_t)o0 * H_;

  f32x4 acc[4][4];
#pragma unroll
  for (int i = 0; i < 4; ++i)
#pragma unroll
    for (int j = 0; j < 4; ++j) acc[i][j] = (f32x4){0.f, 0.f, 0.f, 0.f};

  for (int k0 = 0; k0 < H_; k0 += 64) {
    __syncthreads();
    // A tile fp32: 128 rows x 64 k x 4B = 32 KiB = 2048 granules -> 8 issues/wave
#pragma unroll
    for (int i = 0; i < 8; ++i) {
      int ig = (wave << 3) + i;          // issue-group 0..31
      int p = (ig << 6) + lane;          // physical granule 0..2047
      int row = p >> 4;                  // 16 granules per fp32 row
      int pg = p & 15;
      int lg = (pg & 8) | ((pg & 7) ^ (row & 7));  // logical granule (inverse swz)
      size_t goff = (size_t)row * H_ + k0 + (lg << 2);
      async16(cf + goff, (char*)As + ((size_t)ig << 10));
    }
    // B tile bf16: 128 rows x 64 k x 2B = 16 KiB = 1024 granules -> 4 issues/wave
#pragma unroll
    for (int i = 0; i < 4; ++i) {
      int ig = (wave << 2) + i;
      int p = (ig << 6) + lane;
      int row = p >> 3;
      int gl = (p & 7) ^ (row & 7);
      size_t goff = (size_t)row * H_ + k0 + (gl << 3);
      async16(wb + goff, (char*)Bs + ((size_t)ig << 10));
    }
    __syncthreads();
#pragma unroll
    for (int kk = 0; kk < 2; ++kk) {
      bf16x8 af[4], bfr[4];
#pragma unroll
      for (int i = 0; i < 4; ++i) {
        int row = wm + (i << 4) + m;
        int lg0 = ((kk << 2) + q) << 1;                    // even logical granule
        int ph0 = (lg0 & 8) | ((lg0 & 7) ^ (row & 7));
        int lg1 = lg0 | 1;
        int ph1 = (lg1 & 8) | ((lg1 & 7) ^ (row & 7));
        f32x4 a0 = *(const f32x4*)(As + (row << 6) + (ph0 << 2));
        f32x4 a1 = *(const f32x4*)(As + (row << 6) + (ph1 << 2));
        bf16x8 t;
        t[0] = (__bf16)a0[0]; t[1] = (__bf16)a0[1];
        t[2] = (__bf16)a0[2]; t[3] = (__bf16)a0[3];
        t[4] = (__bf16)a1[0]; t[5] = (__bf16)a1[1];
        t[6] = (__bf16)a1[2]; t[7] = (__bf16)a1[3];
        af[i] = t;
      }
#pragma unroll
      for (int j = 0; j < 4; ++j) {
        int row = wn + (j << 4) + m;
        int gp = ((kk << 2) + q) ^ (row & 7);
        bfr[j] = *(const bf16x8*)(Bs + (row << 6) + (gp << 3));
      }
#pragma unroll
      for (int i = 0; i < 4; ++i)
#pragma unroll
        for (int j = 0; j < 4; ++j)
          acc[i][j] = __builtin_amdgcn_mfma_f32_16x16x32_bf16(af[i], bfr[j], acc[i][j], 0, 0, 0);
    }
  }

  // epilogue: lane holds D[t = wm + i*16 + q*4 + r][o = o0 + wn + j*16 + m]
  float hb[4], vv[4];
#pragma unroll
  for (int j = 0; j < 4; ++j) {
    int o = o0 + wn + (j << 4) + m;
    hb[j] = hxb[(b << 10) + o];
    vv[j] = v[o];
  }
#pragma unroll
  for (int i = 0; i < 4; ++i) {
#pragma unroll
    for (int r = 0; r < 4; ++r) {
      float s = 0.f;
#pragma unroll
      for (int j = 0; j < 4; ++j) s += fast_tanh(acc[i][j][r] + hb[j]) * vv[j];
      s += __shfl_xor(s, 1);
      s += __shfl_xor(s, 2);
      s += __shfl_xor(s, 4);
      s += __shfl_xor(s, 8);
      if (m == 0) atomicAdd(&part[wm + (i << 4) + (q << 2) + r], s);
    }
  }
  __syncthreads();
  if (tid < 128) atomicAdd(&logits[b * T_ + t0 + tid], part[tid]);
}

// Softmax + weighted sum, fp32 ctx (r3-validated consumer; r0 structure).
// Grid (T/128, B). Each block recomputes row softmax from logits (8 KB), handles
// a 128-t chunk; thread owns 4 h columns.
__global__ void wsum_kernel(const float* __restrict__ ctx,
                            const float* __restrict__ logits,
                            float* __restrict__ score, float* __restrict__ outc) {
  int tid = threadIdx.x;
  int b = blockIdx.y;
  int tc = blockIdx.x << 7;
  __shared__ float wred[4];
  __shared__ float sc[128];

  const float* lb = logits + b * T_;
  float l[8];
  float mx = -3.4e38f;
#pragma unroll
  for (int i = 0; i < 8; ++i) { l[i] = lb[tid + (i << 8)]; mx = fmaxf(mx, l[i]); }
#pragma unroll
  for (int d = 1; d < 64; d <<= 1) mx = fmaxf(mx, __shfl_xor(mx, d));
  if ((tid & 63) == 0) wred[tid >> 6] = mx;
  __syncthreads();
  mx = fmaxf(fmaxf(wred[0], wred[1]), fmaxf(wred[2], wred[3]));
  __syncthreads();
  float e[8];
  float se = 0.f;
#pragma unroll
  for (int i = 0; i < 8; ++i) { e[i] = __expf(l[i] - mx); se += e[i]; }
#pragma unroll
  for (int d = 1; d < 64; d <<= 1) se += __shfl_xor(se, d);
  if ((tid & 63) == 0) wred[tid >> 6] = se;
  __syncthreads();
  se = wred[0] + wred[1] + wred[2] + wred[3];
  float inv = 1.0f / se;
#pragma unroll
  for (int i = 0; i < 8; ++i) {
    int tg = tid + (i << 8);
    if ((tg >> 7) == (int)blockIdx.x) sc[tg & 127] = e[i] * inv;
  }
  if (blockIdx.x == 0) {
#pragma unroll
    for (int i = 0; i < 8; ++i) score[b * T_ + tid + (i << 8)] = e[i] * inv;
  }
  __syncthreads();

  int h = tid << 2;
  const float* cp = ctx + ((size_t)b * T_ + tc) * H_ + h;
  float s0 = 0.f, s1 = 0.f, s2 = 0.f, s3 = 0.f;
#pragma unroll 4
  for (int t = 0; t < 128; ++t) {
    float4 f = *(const float4*)(cp + (size_t)t * H_);
    float w = sc[t];
    s0 += f.x * w; s1 += f.y * w; s2 += f.z * w; s3 += f.w * w;
  }
  float* op = outc + (b << 10) + h;
  atomicAdd(op + 0, s0);
  atomicAdd(op + 1, s1);
  atomicAdd(op + 2, s2);
  atomicAdd(op + 3, s3);
}

extern "C" void kernel_launch(void* const* d_in, const int* in_sizes, int n_in,
                              void* d_out, int out_size, void* d_ws, size_t ws_size,
                              hipStream_t stream) {
  const float* x   = (const float*)d_in[0];
  const float* ctx = (const float*)d_in[1];
  // d_in[2] = mask, unused by the reference
  const float* Wq  = (const float*)d_in[3];
  const float* bq  = (const float*)d_in[4];
  const float* Wm  = (const float*)d_in[5];
  const float* bm  = (const float*)d_in[6];
  const float* v   = (const float*)d_in[7];

  float* out_c = (float*)d_out;   // [B,H]
  float* out_s = out_c + B_ * H_; // [B,T]

  // workspace: ~2.5 MiB total (no ctx conversion buffer)
  char* ws = (char*)d_ws;
  float* hxb = (float*)ws;                                        // 128 KiB
  unsigned short* wmb = (unsigned short*)(ws + 131072);           // 2 MiB
  float* logits = (float*)(ws + 131072 + 2097152);                // 256 KiB

  prep_kernel<<<dim3(536), 256, 0, stream>>>(x, Wq, bq, bm, Wm, hxb, wmb,
                                             logits, out_c);
  score_kernel<<<dim3(4096), 256, 0, stream>>>(ctx, wmb, hxb, v, logits);
  wsum_kernel<<<dim3(T_ / 128, B_), 256, 0, stream>>>(ctx, logits, out_s, out_c);
}

// Round 6
// 617.133 us; speedup vs baseline: 1.1803x; 1.1803x over previous
//
#include <hip/hip_runtime.h>
#include <math.h>

#define B_ 32
#define T_ 2048
#define H_ 1024

typedef __bf16 bf16x8 __attribute__((ext_vector_type(8)));
typedef float f32x4 __attribute__((ext_vector_type(4)));

__device__ __forceinline__ unsigned short f2bf(float f) {
  unsigned int u = __float_as_uint(f);
  u += 0x7fffu + ((u >> 16) & 1u);   // round-to-nearest-even (finite inputs)
  return (unsigned short)(u >> 16);
}

__device__ __forceinline__ float bf2f(unsigned short s) {
  return __uint_as_float(((unsigned int)s) << 16);
}

__device__ __forceinline__ float fast_tanh(float x) {
  float e = __expf(2.0f * x);
  return 1.0f - __fdividef(2.0f, e + 1.0f);  // saturates correctly at +-1
}

// Async 16B global -> LDS. LDS dest is wave-uniform base + lane*16 (HW rule).
__device__ __forceinline__ void async16(const void* g, void* l) {
  typedef const __attribute__((address_space(1))) void* gvp;
  typedef __attribute__((address_space(3))) void* lvp;
  __builtin_amdgcn_global_load_lds((gvp)(unsigned long long)g,
                                   (lvp)(unsigned int)(unsigned long long)l,
                                   16, 0, 0);
}

// Re-blocked prep (r4-verified): FEW blocks, LOTS of work each.
// blk ranges:
//  [0,2048):      ctx fp32 -> bf16, 32768 floats/block
//  [2048,2304):   hxb — wave per o: Wq row loaded ONCE, loop over b
//  [2304,2560):   Wm fp32 -> bf16, 4096 floats/block
//  [2560,2576):   zero logits
//  [2576,2584):   zero out_c
__global__ void prep_kernel(const float* __restrict__ x, const float* __restrict__ Wq,
                            const float* __restrict__ bq, const float* __restrict__ bm,
                            const float* __restrict__ Wm, const float* __restrict__ ctx,
                            float* __restrict__ hxb, unsigned short* __restrict__ wmb,
                            unsigned short* __restrict__ ctxb,
                            float* __restrict__ logits, float* __restrict__ outc) {
  int blk = blockIdx.x, tid = threadIdx.x;
  if (blk < 2048) {
    if (ctxb == nullptr) return;
    size_t base = ((size_t)blk << 15) + ((size_t)tid << 3);
#pragma unroll 4
    for (int it = 0; it < 16; ++it) {
      size_t i = base + ((size_t)it << 11);
      float4 a = *(const float4*)(ctx + i);
      float4 c = *(const float4*)(ctx + i + 4);
      *(ushort4*)(ctxb + i) = make_ushort4(f2bf(a.x), f2bf(a.y), f2bf(a.z), f2bf(a.w));
      *(ushort4*)(ctxb + i + 4) = make_ushort4(f2bf(c.x), f2bf(c.y), f2bf(c.z), f2bf(c.w));
    }
  } else if (blk < 2304) {
    int wave = tid >> 6, lane = tid & 63;
    int o = ((blk - 2048) << 2) + wave;
    const float4* wr = (const float4*)(Wq + (size_t)o * H_);
    float4 wv[4];
#pragma unroll
    for (int s4 = 0; s4 < 4; ++s4) wv[s4] = wr[(s4 << 6) + lane];
    float bias = bq[o] + bm[o];
#pragma unroll 4
    for (int b = 0; b < B_; ++b) {
      const float4* xr = (const float4*)(x + (size_t)b * H_);
      float s = 0.f;
#pragma unroll
      for (int s4 = 0; s4 < 4; ++s4) {
        float4 xv = xr[(s4 << 6) + lane];
        s += wv[s4].x * xv.x + wv[s4].y * xv.y + wv[s4].z * xv.z + wv[s4].w * xv.w;
      }
#pragma unroll
      for (int d = 1; d < 64; d <<= 1) s += __shfl_xor(s, d);
      if (lane == 0) hxb[(b << 10) + o] = s + bias;
    }
  } else if (blk < 2560) {
    int i0 = ((blk - 2304) << 12) + (tid << 2);
#pragma unroll
    for (int it = 0; it < 4; ++it) {
      int i = i0 + (it << 10);
      float4 wv = *(const float4*)(Wm + i);
      *(ushort4*)(wmb + i) = make_ushort4(f2bf(wv.x), f2bf(wv.y), f2bf(wv.z), f2bf(wv.w));
    }
  } else if (blk < 2576) {
    int i0 = ((blk - 2560) << 12) + (tid << 2);
#pragma unroll
    for (int it = 0; it < 4; ++it)
      *(float4*)(logits + i0 + (it << 10)) = (float4){0.f, 0.f, 0.f, 0.f};
  } else {
    int i0 = ((blk - 2576) << 12) + (tid << 2);
#pragma unroll
    for (int it = 0; it < 4; ++it)
      *(float4*)(outc + i0 + (it << 10)) = (float4){0.f, 0.f, 0.f, 0.f};
  }
}

// Grid 4096: blockIdx.x = ot*512 + b*16 + tt. One 128t x 128o tile per block.
// r4 GEMM + T3 minimum 2-phase pipeline: LDS double-buffered (2x As + 2x Bs =
// 64 KiB); each k-step ISSUES next tile's global_load_lds first, then computes
// the current tile, then a single __syncthreads() (compiler emits vmcnt(0)
// lgkmcnt(0) drain at the barrier) -> staging latency hides under MFMA phase.
// Read/write patterns per buffer are byte-identical to r4 (conflict-free).
template <bool PRECONV>
__global__ __launch_bounds__(256) void score_kernel(
    const float* __restrict__ ctxf, const unsigned short* __restrict__ ctxb,
    const unsigned short* __restrict__ wmb,
    const float* __restrict__ hxb, const float* __restrict__ v,
    float* logits) {
  __shared__ __align__(16) unsigned short As[2][128 * 64];
  __shared__ __align__(16) unsigned short Bs[2][128 * 64];
  __shared__ float part[128];

  int tid = threadIdx.x;
  int xx = blockIdx.x;
  int ot = xx >> 9;
  int bt = xx & 511;
  int b = bt >> 4;
  int t0 = (bt & 15) << 7;
  int o0 = ot << 7;
  if (tid < 128) part[tid] = 0.f;

  int lane = tid & 63;
  int wave = tid >> 6;
  int wm = (wave >> 1) << 6;  // wave t-offset (0/64)
  int wn = (wave & 1) << 6;   // wave o-offset (0/64)
  int q = lane >> 4;
  int m = lane & 15;

  const unsigned short* cb = PRECONV ? (ctxb + ((size_t)b * T_ + t0) * H_) : nullptr;
  const float* cf = PRECONV ? nullptr : (ctxf + ((size_t)b * T_ + t0) * H_);
  const unsigned short* wb = wmb + (size_t)o0 * H_;

  f32x4 acc[4][4];
#pragma unroll
  for (int i = 0; i < 4; ++i)
#pragma unroll
    for (int j = 0; j < 4; ++j) acc[i][j] = (f32x4){0.f, 0.f, 0.f, 0.f};

  // ---- staging (one k-tile into buffer sel) ----
  auto stage = [&](int sel, int k0) {
#pragma unroll
    for (int i = 0; i < 4; ++i) {
      int ig = (wave << 2) + i;          // issue-group 0..15 (64 granules each)
      int p = (ig << 6) + lane;          // physical granule 0..1023
      int row = p >> 3;
      int gl = (p & 7) ^ (row & 7);      // logical granule (swizzle inverse)
      size_t goff = (size_t)row * H_ + k0 + (gl << 3);
      if (PRECONV) {
        async16(cb + goff, (char*)As[sel] + ((size_t)ig << 10));
      } else {
        int arow = (tid >> 3) + (i << 5);
        int agl = tid & 7;
        int agp = agl ^ (arow & 7);
        const float* src = cf + (size_t)arow * H_ + k0 + (agl << 3);
        float4 f0 = *(const float4*)(src);
        float4 f1 = *(const float4*)(src + 4);
        unsigned short* dst = As[sel] + (arow << 6) + (agp << 3);
        *(ushort4*)(dst) = make_ushort4(f2bf(f0.x), f2bf(f0.y), f2bf(f0.z), f2bf(f0.w));
        *(ushort4*)(dst + 4) = make_ushort4(f2bf(f1.x), f2bf(f1.y), f2bf(f1.z), f2bf(f1.w));
      }
      async16(wb + goff, (char*)Bs[sel] + ((size_t)ig << 10));
    }
  };

  // prologue: fill buffer 0
  stage(0, 0);
  __syncthreads();   // vmcnt(0) drain -> buf0 ready

  for (int ks = 0; ks < 16; ++ks) {
    int cur = ks & 1;
    if (ks < 15) stage(cur ^ 1, (ks + 1) << 6);   // prefetch flies under compute
#pragma unroll
    for (int kk = 0; kk < 2; ++kk) {
      bf16x8 af[4], bfr[4];
#pragma unroll
      for (int i = 0; i < 4; ++i) {
        int row = wm + (i << 4) + m;
        int gp = ((kk << 2) + q) ^ (row & 7);
        af[i] = *(const bf16x8*)(As[cur] + (row << 6) + (gp << 3));
      }
#pragma unroll
      for (int j = 0; j < 4; ++j) {
        int row = wn + (j << 4) + m;
        int gp = ((kk << 2) + q) ^ (row & 7);
        bfr[j] = *(const bf16x8*)(Bs[cur] + (row << 6) + (gp << 3));
      }
#pragma unroll
      for (int i = 0; i < 4; ++i)
#pragma unroll
        for (int j = 0; j < 4; ++j)
          acc[i][j] = __builtin_amdgcn_mfma_f32_16x16x32_bf16(af[i], bfr[j], acc[i][j], 0, 0, 0);
    }
    __syncthreads();  // drains prefetch (vmcnt) + frag reads; waves in lockstep
  }

  // epilogue: lane holds D[t = wm + i*16 + q*4 + r][o = o0 + wn + j*16 + m]
  float hb[4], vv[4];
#pragma unroll
  for (int j = 0; j < 4; ++j) {
    int o = o0 + wn + (j << 4) + m;
    hb[j] = hxb[(b << 10) + o];
    vv[j] = v[o];
  }
#pragma unroll
  for (int i = 0; i < 4; ++i) {
#pragma unroll
    for (int r = 0; r < 4; ++r) {
      float s = 0.f;
#pragma unroll
      for (int j = 0; j < 4; ++j) s += fast_tanh(acc[i][j][r] + hb[j]) * vv[j];
      s += __shfl_xor(s, 1);
      s += __shfl_xor(s, 2);
      s += __shfl_xor(s, 4);
      s += __shfl_xor(s, 8);
      if (m == 0) atomicAdd(&part[wm + (i << 4) + (q << 2) + r], s);
    }
  }
  __syncthreads();
  if (tid < 128) atomicAdd(&logits[b * T_ + t0 + tid], part[tid]);
}

// Fused softmax + weighted sum (r0/r4 verified). Grid (T/128, B).
template <bool PRECONV>
__global__ void wsum_kernel(const float* __restrict__ ctxf, const unsigned short* __restrict__ ctxb,
                            const float* __restrict__ logits,
                            float* __restrict__ score, float* __restrict__ outc) {
  int tid = threadIdx.x;
  int b = blockIdx.y;
  int tc = blockIdx.x << 7;
  __shared__ float wred[4];
  __shared__ float sc[128];

  const float* lb = logits + b * T_;
  float l[8];
  float mx = -3.4e38f;
#pragma unroll
  for (int i = 0; i < 8; ++i) { l[i] = lb[tid + (i << 8)]; mx = fmaxf(mx, l[i]); }
#pragma unroll
  for (int d = 1; d < 64; d <<= 1) mx = fmaxf(mx, __shfl_xor(mx, d));
  if ((tid & 63) == 0) wred[tid >> 6] = mx;
  __syncthreads();
  mx = fmaxf(fmaxf(wred[0], wred[1]), fmaxf(wred[2], wred[3]));
  __syncthreads();
  float e[8];
  float se = 0.f;
#pragma unroll
  for (int i = 0; i < 8; ++i) { e[i] = __expf(l[i] - mx); se += e[i]; }
#pragma unroll
  for (int d = 1; d < 64; d <<= 1) se += __shfl_xor(se, d);
  if ((tid & 63) == 0) wred[tid >> 6] = se;
  __syncthreads();
  se = wred[0] + wred[1] + wred[2] + wred[3];
  float inv = 1.0f / se;
#pragma unroll
  for (int i = 0; i < 8; ++i) {
    int tg = tid + (i << 8);
    if ((tg >> 7) == (int)blockIdx.x) sc[tg & 127] = e[i] * inv;
  }
  if (blockIdx.x == 0) {
#pragma unroll
    for (int i = 0; i < 8; ++i) score[b * T_ + tid + (i << 8)] = e[i] * inv;
  }
  __syncthreads();

  int h = tid << 2;
  float s0 = 0.f, s1 = 0.f, s2 = 0.f, s3 = 0.f;
  if (PRECONV) {
    const unsigned short* cp = ctxb + ((size_t)b * T_ + tc) * H_ + h;
#pragma unroll 4
    for (int t = 0; t < 128; ++t) {
      uint2 u = *(const uint2*)(cp + (size_t)t * H_);
      float w = sc[t];
      s0 += bf2f((unsigned short)(u.x & 0xffffu)) * w;
      s1 += bf2f((unsigned short)(u.x >> 16)) * w;
      s2 += bf2f((unsigned short)(u.y & 0xffffu)) * w;
      s3 += bf2f((unsigned short)(u.y >> 16)) * w;
    }
  } else {
    const float* cp = ctxf + ((size_t)b * T_ + tc) * H_ + h;
#pragma unroll 4
    for (int t = 0; t < 128; ++t) {
      float4 f = *(const float4*)(cp + (size_t)t * H_);
      float w = sc[t];
      s0 += f.x * w; s1 += f.y * w; s2 += f.z * w; s3 += f.w * w;
    }
  }
  float* op = outc + (b << 10) + h;
  atomicAdd(op + 0, s0);
  atomicAdd(op + 1, s1);
  atomicAdd(op + 2, s2);
  atomicAdd(op + 3, s3);
}

extern "C" void kernel_launch(void* const* d_in, const int* in_sizes, int n_in,
                              void* d_out, int out_size, void* d_ws, size_t ws_size,
                              hipStream_t stream) {
  const float* x   = (const float*)d_in[0];
  const float* ctx = (const float*)d_in[1];
  // d_in[2] = mask, unused by the reference
  const float* Wq  = (const float*)d_in[3];
  const float* bq  = (const float*)d_in[4];
  const float* Wm  = (const float*)d_in[5];
  const float* bm  = (const float*)d_in[6];
  const float* v   = (const float*)d_in[7];

  float* out_c = (float*)d_out;   // [B,H]
  float* out_s = out_c + B_ * H_; // [B,T]

  char* ws = (char*)d_ws;
  float* hxb = (float*)ws;                                   // 128 KiB
  unsigned short* wmb = (unsigned short*)(ws + 131072);      // 2 MiB
  float* logits = (float*)(ws + 131072 + 2097152);           // 256 KiB
  size_t off_ctxb = 131072 + 2097152 + 262144;
  unsigned short* ctxb = (unsigned short*)(ws + off_ctxb);   // 128 MiB
  size_t need = off_ctxb + (size_t)B_ * T_ * H_ * 2;
  bool preconv = (ws_size >= need);

  prep_kernel<<<dim3(2584), 256, 0, stream>>>(x, Wq, bq, bm, Wm, ctx, hxb, wmb,
                                              preconv ? ctxb : nullptr, logits, out_c);
  if (preconv) {
    score_kernel<true><<<dim3(4096), 256, 0, stream>>>(ctx, ctxb, wmb, hxb, v, logits);
    wsum_kernel<true><<<dim3(T_ / 128, B_), 256, 0, stream>>>(ctx, ctxb, logits, out_s, out_c);
  } else {
    score_kernel<false><<<dim3(4096), 256, 0, stream>>>(ctx, ctxb, wmb, hxb, v, logits);
    wsum_kernel<false><<<dim3(T_ / 128, B_), 256, 0, stream>>>(ctx, ctxb, logits, out_s, out_c);
  }
}